// Round 1
// baseline (447.776 us; speedup 1.0000x reference)
//
#include <hip/hip_runtime.h>
#include <math.h>

// Problem shape (fixed by setup_inputs)
#define BB 2
#define CC 8
#define NN 16384
#define DD 256
#define HH 64
#define WW 64

// Workspace layout in floats:
//  A    [256x256]  = Wq @ Wk^T              (Wk = Wkv[:, :256])
//  Wvo  [256x256]  = Wv @ Wo                (Wv = Wkv[:, 256:])
//  pb   [256]      = bq @ Wk^T
//  bvo  [256]      = bv @ Wo
//  suma [32768]    = per-row sum of attn (1.0 if any valid else 0.0)
//  p    [32768x256] = layernorm(q) @ A + pb ; overwritten in-place by sbar
#define WS_A    0
#define WS_WVO  65536
#define WS_PB   131072
#define WS_BVO  131328
#define WS_SUMA 131584
#define WS_P    164352
// total = 164352 + 8388608 floats = 34.2 MB

__global__ __launch_bounds__(256)
void precompute_kernel(const float* __restrict__ Wq, const float* __restrict__ bq,
                       const float* __restrict__ Wkv, const float* __restrict__ bkv,
                       const float* __restrict__ Wo, float* __restrict__ ws) {
    int t = threadIdx.x;
    int blk = blockIdx.x;
    if (blk < 256) {
        // A[f][e] = sum_d Wq[f,d] * Wkv[e,d]   (both K-contiguous)
        int f = blk;
        const float4* wq4 = (const float4*)(Wq + f * 256);
        const float4* wk4 = (const float4*)(Wkv + (long)t * 512);
        float acc = 0.f;
        #pragma unroll 8
        for (int d4 = 0; d4 < 64; ++d4) {
            float4 a = wq4[d4], b = wk4[d4];
            acc += a.x * b.x + a.y * b.y + a.z * b.z + a.w * b.w;
        }
        ws[WS_A + f * 256 + t] = acc;
    } else if (blk < 512) {
        // Wvo[e][d] = sum_g Wkv[e, 256+g] * Wo[g,d]
        int e = blk - 256;
        float acc = 0.f;
        for (int g = 0; g < 256; ++g)
            acc = fmaf(Wkv[(long)e * 512 + 256 + g], Wo[g * 256 + t], acc);
        ws[WS_WVO + e * 256 + t] = acc;
    } else if (blk == 512) {
        // pb[e] = sum_d bq[d] * Wkv[e,d]
        float acc = 0.f;
        for (int d = 0; d < 256; ++d)
            acc = fmaf(bq[d], Wkv[(long)t * 512 + d], acc);
        ws[WS_PB + t] = acc;
    } else {
        // bvo[d] = sum_g bkv[256+g] * Wo[g,d]
        float acc = 0.f;
        for (int g = 0; g < 256; ++g)
            acc = fmaf(bkv[256 + g], Wo[g * 256 + t], acc);
        ws[WS_BVO + t] = acc;
    }
}

// Fused layernorm + p = qn @ A + pb.  16 rows per 256-thread block.
__global__ __launch_bounds__(256)
void ln_p_kernel(const float* __restrict__ queries, const float* __restrict__ gamma,
                 const float* __restrict__ beta, float* __restrict__ ws) {
    __shared__ float qs[16][256];
    const float* Amat = ws + WS_A;
    const float* pb   = ws + WS_PB;
    float* pbuf = ws + WS_P;
    int tid = threadIdx.x, wave = tid >> 6, lane = tid & 63;
    long row0 = (long)blockIdx.x * 16;

    float4 g4 = *(const float4*)(gamma + 4 * lane);
    float4 b4 = *(const float4*)(beta + 4 * lane);
    #pragma unroll
    for (int rr = 0; rr < 4; ++rr) {
        int r = wave * 4 + rr;
        float4 v = *(const float4*)(queries + (row0 + r) * 256 + 4 * lane);
        float s = v.x + v.y + v.z + v.w;
        s += __shfl_xor(s, 32); s += __shfl_xor(s, 16); s += __shfl_xor(s, 8);
        s += __shfl_xor(s, 4);  s += __shfl_xor(s, 2);  s += __shfl_xor(s, 1);
        float mu = s * 0.00390625f;
        float dx = v.x - mu, dy = v.y - mu, dz = v.z - mu, dw = v.w - mu;
        float vv = dx * dx + dy * dy + dz * dz + dw * dw;
        vv += __shfl_xor(vv, 32); vv += __shfl_xor(vv, 16); vv += __shfl_xor(vv, 8);
        vv += __shfl_xor(vv, 4);  vv += __shfl_xor(vv, 2);  vv += __shfl_xor(vv, 1);
        float rstd = rsqrtf(vv * 0.00390625f + 1e-5f);
        float4 qn;
        qn.x = dx * rstd * g4.x + b4.x;
        qn.y = dy * rstd * g4.y + b4.y;
        qn.z = dz * rstd * g4.z + b4.z;
        qn.w = dw * rstd * g4.w + b4.w;
        *(float4*)(&qs[r][4 * lane]) = qn;
    }
    __syncthreads();

    int e = tid;
    float acc[16];
    float pbe = pb[e];
    #pragma unroll
    for (int r = 0; r < 16; ++r) acc[r] = pbe;
    for (int f4 = 0; f4 < 64; ++f4) {
        float a0 = Amat[(4 * f4 + 0) * 256 + e];
        float a1 = Amat[(4 * f4 + 1) * 256 + e];
        float a2 = Amat[(4 * f4 + 2) * 256 + e];
        float a3 = Amat[(4 * f4 + 3) * 256 + e];
        #pragma unroll
        for (int r = 0; r < 16; ++r) {
            float4 q = *(const float4*)(&qs[r][4 * f4]);
            acc[r] = fmaf(q.x, a0, acc[r]);
            acc[r] = fmaf(q.y, a1, acc[r]);
            acc[r] = fmaf(q.z, a2, acc[r]);
            acc[r] = fmaf(q.w, a3, acc[r]);
        }
    }
    #pragma unroll
    for (int r = 0; r < 16; ++r)
        pbuf[(row0 + r) * 256 + e] = acc[r];
}

// One wave per query row: bilinear-sample 8 contexts, score vs p, softmax,
// weighted feature sum sbar. Writes sbar in-place over p.
__global__ __launch_bounds__(256)
void sample_attn_kernel(const float* __restrict__ feat, const float* __restrict__ coords,
                        const int* __restrict__ vmask, float* __restrict__ ws) {
    float* pbuf = ws + WS_P;
    float* suma = ws + WS_SUMA;
    int tid = threadIdx.x, wave = tid >> 6, lane = tid & 63;
    long row = (long)blockIdx.x * 4 + wave;           // 0..32767
    int b = (int)(row >> 14);
    int n = (int)(row & 16383);

    float4 p4 = *(const float4*)(pbuf + row * 256 + 4 * lane);

    float4 sc[8];
    float score[8];
    bool vld[8];
    #pragma unroll
    for (int c = 0; c < 8; ++c) {
        long cb = (long)(b * 8 + c) * 16384 + n;
        float cx = coords[2 * cb];
        float cy = coords[2 * cb + 1];
        vld[c] = (vmask[cb] != 0);
        float x = (cx + 1.f) * 31.5f;   // (c+1)*0.5*(W-1)
        float y = (cy + 1.f) * 31.5f;
        float x0f = floorf(x), y0f = floorf(y);
        float wx = x - x0f, wy = y - y0f;
        int ix0 = (int)x0f, iy0 = (int)y0f;
        int ix1 = ix0 + 1, iy1 = iy0 + 1;
        float bx0 = (ix0 >= 0 && ix0 < WW) ? 1.f : 0.f;
        float bx1 = (ix1 >= 0 && ix1 < WW) ? 1.f : 0.f;
        float by0 = (iy0 >= 0 && iy0 < HH) ? 1.f : 0.f;
        float by1 = (iy1 >= 0 && iy1 < HH) ? 1.f : 0.f;
        int cx0 = min(max(ix0, 0), WW - 1), cx1 = min(max(ix1, 0), WW - 1);
        int cy0 = min(max(iy0, 0), HH - 1), cy1 = min(max(iy1, 0), HH - 1);
        const float* fb = feat + ((long)(b * 8 + c) << 20);   // 64*64*256
        const float* r00 = fb + ((cy0 * 64 + cx0) << 8) + 4 * lane;
        const float* r01 = fb + ((cy0 * 64 + cx1) << 8) + 4 * lane;
        const float* r10 = fb + ((cy1 * 64 + cx0) << 8) + 4 * lane;
        const float* r11 = fb + ((cy1 * 64 + cx1) << 8) + 4 * lane;
        float w00 = (1.f - wy) * (1.f - wx) * by0 * bx0;
        float w01 = (1.f - wy) * wx * by0 * bx1;
        float w10 = wy * (1.f - wx) * by1 * bx0;
        float w11 = wy * wx * by1 * bx1;
        float4 v00 = *(const float4*)r00;
        float4 v01 = *(const float4*)r01;
        float4 v10 = *(const float4*)r10;
        float4 v11 = *(const float4*)r11;
        float4 s;
        s.x = w00 * v00.x + w01 * v01.x + w10 * v10.x + w11 * v11.x;
        s.y = w00 * v00.y + w01 * v01.y + w10 * v10.y + w11 * v11.y;
        s.z = w00 * v00.z + w01 * v01.z + w10 * v10.z + w11 * v11.z;
        s.w = w00 * v00.w + w01 * v01.w + w10 * v10.w + w11 * v11.w;
        sc[c] = s;
        float t = s.x * p4.x + s.y * p4.y + s.z * p4.z + s.w * p4.w;
        t += __shfl_xor(t, 32); t += __shfl_xor(t, 16); t += __shfl_xor(t, 8);
        t += __shfl_xor(t, 4);  t += __shfl_xor(t, 2);  t += __shfl_xor(t, 1);
        score[c] = t * 0.0625f;   // / sqrt(256)
    }

    float m = -INFINITY;
    #pragma unroll
    for (int c = 0; c < 8; ++c) if (vld[c]) m = fmaxf(m, score[c]);
    float4 sb = {0.f, 0.f, 0.f, 0.f};
    float sa = 0.f;
    if (m > -INFINITY) {
        float w[8], s = 0.f;
        #pragma unroll
        for (int c = 0; c < 8; ++c) { w[c] = vld[c] ? expf(score[c] - m) : 0.f; s += w[c]; }
        float inv = 1.f / s;
        #pragma unroll
        for (int c = 0; c < 8; ++c) {
            float a = w[c] * inv;
            sb.x = fmaf(a, sc[c].x, sb.x);
            sb.y = fmaf(a, sc[c].y, sb.y);
            sb.z = fmaf(a, sc[c].z, sb.z);
            sb.w = fmaf(a, sc[c].w, sb.w);
        }
        sa = 1.f;
    }
    *(float4*)(pbuf + row * 256 + 4 * lane) = sb;   // sbar overwrites p in-place
    if (lane == 0) suma[row] = sa;
}

// out = residual + sbar @ Wvo + suma*bvo + bo.  16 rows per block.
__global__ __launch_bounds__(256)
void final_kernel(const float* __restrict__ queries, const float* __restrict__ bo,
                  const float* __restrict__ ws, float* __restrict__ out) {
    __shared__ float ss[16][256];
    const float* Wvo  = ws + WS_WVO;
    const float* bvo  = ws + WS_BVO;
    const float* suma = ws + WS_SUMA;
    const float* sbar = ws + WS_P;
    int tid = threadIdx.x, wave = tid >> 6, lane = tid & 63;
    long row0 = (long)blockIdx.x * 16;
    #pragma unroll
    for (int rr = 0; rr < 4; ++rr) {
        int r = wave * 4 + rr;
        *(float4*)(&ss[r][4 * lane]) = *(const float4*)(sbar + (row0 + r) * 256 + 4 * lane);
    }
    __syncthreads();

    int e = tid;
    float acc[16];
    #pragma unroll
    for (int r = 0; r < 16; ++r) acc[r] = 0.f;
    for (int f4 = 0; f4 < 64; ++f4) {
        float a0 = Wvo[(4 * f4 + 0) * 256 + e];
        float a1 = Wvo[(4 * f4 + 1) * 256 + e];
        float a2 = Wvo[(4 * f4 + 2) * 256 + e];
        float a3 = Wvo[(4 * f4 + 3) * 256 + e];
        #pragma unroll
        for (int r = 0; r < 16; ++r) {
            float4 q = *(const float4*)(&ss[r][4 * f4]);
            acc[r] = fmaf(q.x, a0, acc[r]);
            acc[r] = fmaf(q.y, a1, acc[r]);
            acc[r] = fmaf(q.z, a2, acc[r]);
            acc[r] = fmaf(q.w, a3, acc[r]);
        }
    }
    float bvoe = bvo[e], boe = bo[e];
    #pragma unroll
    for (int r = 0; r < 16; ++r) {
        long row = row0 + r;
        out[row * 256 + e] = queries[row * 256 + e] + acc[r] + suma[row] * bvoe + boe;
    }
}

extern "C" void kernel_launch(void* const* d_in, const int* in_sizes, int n_in,
                              void* d_out, int out_size, void* d_ws, size_t ws_size,
                              hipStream_t stream) {
    const float* queries = (const float*)d_in[0];
    const float* feat    = (const float*)d_in[1];
    const float* coords  = (const float*)d_in[2];
    const int*   vmask   = (const int*)  d_in[3];
    const float* Wq      = (const float*)d_in[4];
    const float* bq      = (const float*)d_in[5];
    const float* Wkv     = (const float*)d_in[6];
    const float* bkv     = (const float*)d_in[7];
    const float* Wo      = (const float*)d_in[8];
    const float* bo      = (const float*)d_in[9];
    const float* gamma   = (const float*)d_in[10];
    const float* beta    = (const float*)d_in[11];
    float* out = (float*)d_out;
    float* ws  = (float*)d_ws;

    precompute_kernel<<<514, 256, 0, stream>>>(Wq, bq, Wkv, bkv, Wo, ws);
    ln_p_kernel<<<2048, 256, 0, stream>>>(queries, gamma, beta, ws);
    sample_attn_kernel<<<8192, 256, 0, stream>>>(feat, coords, vmask, ws);
    final_kernel<<<2048, 256, 0, stream>>>(queries, bo, ws, out);
}

// Round 2
// 278.334 us; speedup vs baseline: 1.6088x; 1.6088x over previous
//
#include <hip/hip_runtime.h>
#include <math.h>

// Shape: B=2 C=8 N=16384 D=256 H=W=64 ; rows = B*N = 32768
#define NROWS 32768

typedef __attribute__((ext_vector_type(8))) short short8;
typedef __attribute__((ext_vector_type(4))) float f32x4;

// Workspace layout (units of float):
//  ABF    ushort[256*256]  A^T in bf16:   Abf[e*256+f] = bf16(sum_d Wq[f,d]*Wk[e,d])
//  WVOBF  ushort[256*256]  Wvo^T in bf16: Wvobf[d*256+e] = bf16(sum_g Wv[e,g]*Wo[g,d])
//  PB     float[256]       bq @ Wk^T
//  BVO    float[256]       bv @ Wo
//  SUMA   float[32768]     1.0 if any valid context else 0.0
//  P      float[32768*256] p = LN(q)@A + pb ; rows overwritten in-place by bf16 sbar
//  FEATBF ushort[2*8*64*64*256]  bf16 copy of image_features
#define WS_ABF    0
#define WS_WVOBF  32768
#define WS_PB     65536
#define WS_BVO    65792
#define WS_SUMA   66048
#define WS_P      98816
#define WS_FEATBF 8487424
// total = 16876032 floats = 67.5 MB

__device__ __forceinline__ unsigned short f2bf(float f) {
    unsigned u = __builtin_bit_cast(unsigned, f);
    u += 0x7FFFu + ((u >> 16) & 1u);          // RNE
    return (unsigned short)(u >> 16);
}
__device__ __forceinline__ float bf_lo(unsigned u) {
    return __builtin_bit_cast(float, u << 16);
}
__device__ __forceinline__ float bf_hi(unsigned u) {
    return __builtin_bit_cast(float, u & 0xFFFF0000u);
}

// ---------------- precompute: A^T(bf16), Wvo^T(bf16), pb, bvo, feat->bf16 -------------
__global__ __launch_bounds__(256)
void precompute_kernel(const float* __restrict__ Wq, const float* __restrict__ bq,
                       const float* __restrict__ Wkv, const float* __restrict__ bkv,
                       const float* __restrict__ Wo, const float* __restrict__ feat,
                       float* __restrict__ ws) {
    int t = threadIdx.x;
    int blk = blockIdx.x;
    if (blk >= 514) {
        // feature map fp32 -> bf16, 1024 elems per block
        long i = (long)(blk - 514) * 1024 + t * 4;
        float4 v = *(const float4*)(feat + i);
        unsigned lo = (unsigned)f2bf(v.x) | ((unsigned)f2bf(v.y) << 16);
        unsigned hi = (unsigned)f2bf(v.z) | ((unsigned)f2bf(v.w) << 16);
        *(uint2*)((unsigned short*)(ws + WS_FEATBF) + i) = make_uint2(lo, hi);
        return;
    }
    if (blk < 256) {
        // Abf[e][f] = bf16( Wq[f,:] . Wk[e,:] ),  f = blk, e = t
        int f = blk;
        const float4* wq4 = (const float4*)(Wq + f * 256);
        const float4* wk4 = (const float4*)(Wkv + (long)t * 512);
        float acc = 0.f;
        #pragma unroll 8
        for (int d4 = 0; d4 < 64; ++d4) {
            float4 a = wq4[d4], b = wk4[d4];
            acc += a.x * b.x + a.y * b.y + a.z * b.z + a.w * b.w;
        }
        ((unsigned short*)(ws + WS_ABF))[t * 256 + f] = f2bf(acc);
    } else if (blk < 512) {
        // Wvobf[d][e] = bf16( sum_g Wkv[e,256+g] * Wo[g,d] ),  e = blk-256, d = t
        int e = blk - 256;
        float acc = 0.f;
        for (int g = 0; g < 256; ++g)
            acc = fmaf(Wkv[(long)e * 512 + 256 + g], Wo[g * 256 + t], acc);
        ((unsigned short*)(ws + WS_WVOBF))[t * 256 + e] = f2bf(acc);
    } else if (blk == 512) {
        float acc = 0.f;
        for (int d = 0; d < 256; ++d)
            acc = fmaf(bq[d], Wkv[(long)t * 512 + d], acc);
        ws[WS_PB + t] = acc;
    } else {
        float acc = 0.f;
        for (int g = 0; g < 256; ++g)
            acc = fmaf(bkv[256 + g], Wo[g * 256 + t], acc);
        ws[WS_BVO + t] = acc;
    }
}

// ---------------- fused layernorm + p = LN(q)@A + pb  (bf16 MFMA) ---------------------
// 64 rows per block, 4 waves; wave w owns output columns [64w, 64w+64)
__global__ __launch_bounds__(256)
void ln_p_mfma(const float* __restrict__ queries, const float* __restrict__ gamma,
               const float* __restrict__ beta, float* __restrict__ ws) {
    __shared__ unsigned short qs[64][264];   // bf16 LN(q) tile, padded (+8) for LDS banks
    const unsigned short* Abf = (const unsigned short*)(ws + WS_ABF);
    const float* pb = ws + WS_PB;
    float* pbuf = ws + WS_P;
    int tid = threadIdx.x, wave = tid >> 6, lane = tid & 63;
    long row0 = (long)blockIdx.x * 64;

    float4 g4 = *(const float4*)(gamma + 4 * lane);
    float4 b4 = *(const float4*)(beta + 4 * lane);
    for (int rr = 0; rr < 16; ++rr) {
        int r = wave * 16 + rr;
        float4 v = *(const float4*)(queries + (row0 + r) * 256 + 4 * lane);
        float s = v.x + v.y + v.z + v.w;
        s += __shfl_xor(s, 32); s += __shfl_xor(s, 16); s += __shfl_xor(s, 8);
        s += __shfl_xor(s, 4);  s += __shfl_xor(s, 2);  s += __shfl_xor(s, 1);
        float mu = s * 0.00390625f;
        float dx = v.x - mu, dy = v.y - mu, dz = v.z - mu, dw = v.w - mu;
        float vv = dx * dx + dy * dy + dz * dz + dw * dw;
        vv += __shfl_xor(vv, 32); vv += __shfl_xor(vv, 16); vv += __shfl_xor(vv, 8);
        vv += __shfl_xor(vv, 4);  vv += __shfl_xor(vv, 2);  vv += __shfl_xor(vv, 1);
        float rstd = rsqrtf(vv * 0.00390625f + 1e-5f);
        float qx = dx * rstd * g4.x + b4.x;
        float qy = dy * rstd * g4.y + b4.y;
        float qz = dz * rstd * g4.z + b4.z;
        float qw = dw * rstd * g4.w + b4.w;
        unsigned lo = (unsigned)f2bf(qx) | ((unsigned)f2bf(qy) << 16);
        unsigned hi = (unsigned)f2bf(qz) | ((unsigned)f2bf(qw) << 16);
        *(uint2*)&qs[r][4 * lane] = make_uint2(lo, hi);
    }
    __syncthreads();

    int r16 = lane & 15, g = lane >> 4;
    f32x4 zero = {0.f, 0.f, 0.f, 0.f};
    f32x4 acc[4][4];
    #pragma unroll
    for (int mt = 0; mt < 4; ++mt)
        #pragma unroll
        for (int nt = 0; nt < 4; ++nt) acc[mt][nt] = zero;

    #pragma unroll
    for (int ks = 0; ks < 8; ++ks) {
        short8 bfr[4], afr[4];
        #pragma unroll
        for (int nt = 0; nt < 4; ++nt)
            bfr[nt] = *(const short8*)(Abf + ((wave * 64 + nt * 16 + r16) << 8) + ks * 32 + g * 8);
        #pragma unroll
        for (int mt = 0; mt < 4; ++mt)
            afr[mt] = *(const short8*)(&qs[mt * 16 + r16][ks * 32 + g * 8]);
        #pragma unroll
        for (int mt = 0; mt < 4; ++mt)
            #pragma unroll
            for (int nt = 0; nt < 4; ++nt)
                acc[mt][nt] = __builtin_amdgcn_mfma_f32_16x16x32_bf16(afr[mt], bfr[nt], acc[mt][nt], 0, 0, 0);
    }

    float pbv[4];
    #pragma unroll
    for (int nt = 0; nt < 4; ++nt) pbv[nt] = pb[wave * 64 + nt * 16 + r16];
    #pragma unroll
    for (int mt = 0; mt < 4; ++mt)
        #pragma unroll
        for (int nt = 0; nt < 4; ++nt)
            #pragma unroll
            for (int rg = 0; rg < 4; ++rg)
                pbuf[(row0 + mt * 16 + g * 4 + rg) * 256 + wave * 64 + nt * 16 + r16] =
                    acc[mt][nt][rg] + pbv[nt];
}

// ---------------- sample + score + softmax + weighted sum (bf16 gather) ---------------
// one wave per query row; sbar written bf16 in-place over p's row storage
__global__ __launch_bounds__(256)
void sample_attn_bf(const float* __restrict__ coords, const int* __restrict__ vmask,
                    float* __restrict__ ws) {
    float* pbuf = ws + WS_P;
    float* suma = ws + WS_SUMA;
    const unsigned short* featbf = (const unsigned short*)(ws + WS_FEATBF);
    int tid = threadIdx.x, wave = tid >> 6, lane = tid & 63;
    long row = (long)blockIdx.x * 4 + wave;
    int b = (int)(row >> 14);
    int n = (int)(row & 16383);

    float4 p4 = *(const float4*)(pbuf + row * 256 + 4 * lane);

    float4 sc[8];
    float score[8];
    bool vld[8];
    #pragma unroll
    for (int c = 0; c < 8; ++c) {
        long cb = (long)(b * 8 + c) * 16384 + n;
        float cx = coords[2 * cb];
        float cy = coords[2 * cb + 1];
        vld[c] = (vmask[cb] != 0);
        float x = (cx + 1.f) * 31.5f;
        float y = (cy + 1.f) * 31.5f;
        float x0f = floorf(x), y0f = floorf(y);
        float wx = x - x0f, wy = y - y0f;
        int ix0 = (int)x0f, iy0 = (int)y0f;
        int ix1 = ix0 + 1, iy1 = iy0 + 1;
        float bx0 = (ix0 >= 0 && ix0 < 64) ? 1.f : 0.f;
        float bx1 = (ix1 >= 0 && ix1 < 64) ? 1.f : 0.f;
        float by0 = (iy0 >= 0 && iy0 < 64) ? 1.f : 0.f;
        float by1 = (iy1 >= 0 && iy1 < 64) ? 1.f : 0.f;
        int cx0 = min(max(ix0, 0), 63), cx1 = min(max(ix1, 0), 63);
        int cy0 = min(max(iy0, 0), 63), cy1 = min(max(iy1, 0), 63);
        const unsigned short* fb = featbf + ((long)(b * 8 + c) << 20);
        const uint2* r00 = (const uint2*)(fb + ((cy0 * 64 + cx0) << 8)) + lane;
        const uint2* r01 = (const uint2*)(fb + ((cy0 * 64 + cx1) << 8)) + lane;
        const uint2* r10 = (const uint2*)(fb + ((cy1 * 64 + cx0) << 8)) + lane;
        const uint2* r11 = (const uint2*)(fb + ((cy1 * 64 + cx1) << 8)) + lane;
        float w00 = (1.f - wy) * (1.f - wx) * by0 * bx0;
        float w01 = (1.f - wy) * wx * by0 * bx1;
        float w10 = wy * (1.f - wx) * by1 * bx0;
        float w11 = wy * wx * by1 * bx1;
        uint2 v00 = *r00, v01 = *r01, v10 = *r10, v11 = *r11;
        float4 s;
        s.x = w00 * bf_lo(v00.x) + w01 * bf_lo(v01.x) + w10 * bf_lo(v10.x) + w11 * bf_lo(v11.x);
        s.y = w00 * bf_hi(v00.x) + w01 * bf_hi(v01.x) + w10 * bf_hi(v10.x) + w11 * bf_hi(v11.x);
        s.z = w00 * bf_lo(v00.y) + w01 * bf_lo(v01.y) + w10 * bf_lo(v10.y) + w11 * bf_lo(v11.y);
        s.w = w00 * bf_hi(v00.y) + w01 * bf_hi(v01.y) + w10 * bf_hi(v10.y) + w11 * bf_hi(v11.y);
        sc[c] = s;
        float t = s.x * p4.x + s.y * p4.y + s.z * p4.z + s.w * p4.w;
        t += __shfl_xor(t, 32); t += __shfl_xor(t, 16); t += __shfl_xor(t, 8);
        t += __shfl_xor(t, 4);  t += __shfl_xor(t, 2);  t += __shfl_xor(t, 1);
        score[c] = t * 0.0625f;
    }

    float m = -INFINITY;
    #pragma unroll
    for (int c = 0; c < 8; ++c) if (vld[c]) m = fmaxf(m, score[c]);
    float4 sb = {0.f, 0.f, 0.f, 0.f};
    float sa = 0.f;
    if (m > -INFINITY) {
        float w[8], s = 0.f;
        #pragma unroll
        for (int c = 0; c < 8; ++c) { w[c] = vld[c] ? expf(score[c] - m) : 0.f; s += w[c]; }
        float inv = 1.f / s;
        #pragma unroll
        for (int c = 0; c < 8; ++c) {
            float a = w[c] * inv;
            sb.x = fmaf(a, sc[c].x, sb.x);
            sb.y = fmaf(a, sc[c].y, sb.y);
            sb.z = fmaf(a, sc[c].z, sb.z);
            sb.w = fmaf(a, sc[c].w, sb.w);
        }
        sa = 1.f;
    }
    // sbar as bf16, packed into the first 512B of this row's p storage
    unsigned lo = (unsigned)f2bf(sb.x) | ((unsigned)f2bf(sb.y) << 16);
    unsigned hi = (unsigned)f2bf(sb.z) | ((unsigned)f2bf(sb.w) << 16);
    ((uint2*)((char*)pbuf + row * 1024))[lane] = make_uint2(lo, hi);
    if (lane == 0) suma[row] = sa;
}

// ---------------- out = residual + sbar@Wvo + suma*bvo + bo  (bf16 MFMA) --------------
__global__ __launch_bounds__(256)
void final_mfma(const float* __restrict__ queries, const float* __restrict__ bo,
                const float* __restrict__ ws, float* __restrict__ out) {
    __shared__ unsigned short qs[64][264];
    __shared__ float ssu[64];
    const unsigned short* Wvobf = (const unsigned short*)(ws + WS_WVOBF);
    const float* bvo = ws + WS_BVO;
    const float* suma = ws + WS_SUMA;
    const float* pbuf = ws + WS_P;
    int tid = threadIdx.x, wave = tid >> 6, lane = tid & 63;
    long row0 = (long)blockIdx.x * 64;

    for (int rr = 0; rr < 16; ++rr) {
        int r = wave * 16 + rr;
        uint2 v = ((const uint2*)((const char*)pbuf + (row0 + r) * 1024))[lane];
        *(uint2*)&qs[r][4 * lane] = v;
    }
    if (tid < 64) ssu[tid] = suma[row0 + tid];
    __syncthreads();

    int r16 = lane & 15, g = lane >> 4;
    f32x4 zero = {0.f, 0.f, 0.f, 0.f};
    f32x4 acc[4][4];
    #pragma unroll
    for (int mt = 0; mt < 4; ++mt)
        #pragma unroll
        for (int nt = 0; nt < 4; ++nt) acc[mt][nt] = zero;

    #pragma unroll
    for (int ks = 0; ks < 8; ++ks) {
        short8 bfr[4], afr[4];
        #pragma unroll
        for (int nt = 0; nt < 4; ++nt)
            bfr[nt] = *(const short8*)(Wvobf + ((wave * 64 + nt * 16 + r16) << 8) + ks * 32 + g * 8);
        #pragma unroll
        for (int mt = 0; mt < 4; ++mt)
            afr[mt] = *(const short8*)(&qs[mt * 16 + r16][ks * 32 + g * 8]);
        #pragma unroll
        for (int mt = 0; mt < 4; ++mt)
            #pragma unroll
            for (int nt = 0; nt < 4; ++nt)
                acc[mt][nt] = __builtin_amdgcn_mfma_f32_16x16x32_bf16(afr[mt], bfr[nt], acc[mt][nt], 0, 0, 0);
    }

    float bvov[4], bov[4];
    #pragma unroll
    for (int nt = 0; nt < 4; ++nt) {
        int col = wave * 64 + nt * 16 + r16;
        bvov[nt] = bvo[col];
        bov[nt] = bo[col];
    }
    #pragma unroll
    for (int mt = 0; mt < 4; ++mt)
        #pragma unroll
        for (int nt = 0; nt < 4; ++nt)
            #pragma unroll
            for (int rg = 0; rg < 4; ++rg) {
                long row = row0 + mt * 16 + g * 4 + rg;
                int col = wave * 64 + nt * 16 + r16;
                out[row * 256 + col] = queries[row * 256 + col] + acc[mt][nt][rg]
                                     + ssu[mt * 16 + g * 4 + rg] * bvov[nt] + bov[nt];
            }
}

extern "C" void kernel_launch(void* const* d_in, const int* in_sizes, int n_in,
                              void* d_out, int out_size, void* d_ws, size_t ws_size,
                              hipStream_t stream) {
    const float* queries = (const float*)d_in[0];
    const float* feat    = (const float*)d_in[1];
    const float* coords  = (const float*)d_in[2];
    const int*   vmask   = (const int*)  d_in[3];
    const float* Wq      = (const float*)d_in[4];
    const float* bq      = (const float*)d_in[5];
    const float* Wkv     = (const float*)d_in[6];
    const float* bkv     = (const float*)d_in[7];
    const float* Wo      = (const float*)d_in[8];
    const float* bo      = (const float*)d_in[9];
    const float* gamma   = (const float*)d_in[10];
    const float* beta    = (const float*)d_in[11];
    float* out = (float*)d_out;
    float* ws  = (float*)d_ws;

    precompute_kernel<<<514 + 16384, 256, 0, stream>>>(Wq, bq, Wkv, bkv, Wo, feat, ws);
    ln_p_mfma<<<NROWS / 64, 256, 0, stream>>>(queries, gamma, beta, ws);
    sample_attn_bf<<<NROWS / 4, 256, 0, stream>>>(coords, vmask, ws);
    final_mfma<<<NROWS / 64, 256, 0, stream>>>(queries, bo, ws, out);
}